// Round 4
// baseline (1117.717 us; speedup 1.0000x reference)
//
#include <hip/hip_runtime.h>
#include <math.h>

// PointNet++ SA: FPS -> ball query -> gather -> 3x(1x1conv+BN+ReLU) -> maxpool(K)
// R3: FPS v4 — 256 thr/4 waves, DPP idx-min (no shfl), LDS spin-flag sync (no barrier).

static constexpr int BATCH  = 16;
static constexpr int NPTS   = 4096;
static constexpr int NPOINT = 1024;
static constexpr int NSAMP  = 32;
static constexpr int CIN    = 64;
static constexpr int ROWS   = BATCH * NPOINT * NSAMP;  // 524288
static constexpr int NBLK   = ROWS / 64;               // 8192

typedef unsigned long long u64;

__device__ __forceinline__ float sqdist(float x, float y, float z,
                                        float cx, float cy, float cz) {
    // exact IEEE order: (dx*dx + dy*dy) + dz*dz, no fma contraction (matches reference f32)
    float dx = x - cx, dy = y - cy, dz = z - cz;
    return __fadd_rn(__fadd_rn(__fmul_rn(dx, dx), __fmul_rn(dy, dy)), __fmul_rn(dz, dz));
}

#if __has_builtin(__builtin_amdgcn_update_dpp) && __has_builtin(__builtin_amdgcn_readlane)
#define DPP_FMAX(x, ctrl)                                                             \
    do {                                                                              \
        int _o = __builtin_amdgcn_update_dpp(__float_as_int(x), __float_as_int(x),    \
                                             (ctrl), 0xf, 0xf, false);                \
        (x) = fmaxf((x), __int_as_float(_o));                                         \
    } while (0)
#define DPP_UMAX(x, ctrl)                                                             \
    do {                                                                              \
        unsigned _o = (unsigned)__builtin_amdgcn_update_dpp((int)(x), (int)(x),       \
                                                            (ctrl), 0xf, 0xf, false); \
        (x) = ((x) > _o) ? (x) : _o;                                                  \
    } while (0)
// After chain, lane 63 holds the wave max.
#define WAVE_RED_F(x) do { DPP_FMAX(x,0x111); DPP_FMAX(x,0x112); DPP_FMAX(x,0x114); \
                           DPP_FMAX(x,0x118); DPP_FMAX(x,0x142); DPP_FMAX(x,0x143); } while (0)
#define WAVE_RED_U(x) do { DPP_UMAX(x,0x111); DPP_UMAX(x,0x112); DPP_UMAX(x,0x114); \
                           DPP_UMAX(x,0x118); DPP_UMAX(x,0x142); DPP_UMAX(x,0x143); } while (0)
__device__ __forceinline__ float bcast63(float v) {
    return __int_as_float(__builtin_amdgcn_readlane(__float_as_int(v), 63));
}
#else
#define WAVE_RED_F(x) do { for (int _m = 1; _m < 64; _m <<= 1) (x) = fmaxf((x), __shfl_xor((x), _m)); } while (0)
#define WAVE_RED_U(x) do { for (int _m = 1; _m < 64; _m <<= 1) { unsigned _o = __shfl_xor((x), _m); (x) = ((x) > _o) ? (x) : _o; } } while (0)
__device__ __forceinline__ float bcast63(float v) { return __shfl(v, 63); }
#endif

// ---------------- fused: blocks [0,16) = FPS per batch; [16,1040) = P GEMM tiles ----
__global__ __launch_bounds__(256) void pre_kernel(
    const float* __restrict__ xyz, const float* __restrict__ points,
    const float* __restrict__ w0, const float* __restrict__ b0,
    float* __restrict__ P, float* __restrict__ new_xyz) {
    __shared__ __align__(16) char s_raw[53376];
    const int tid = threadIdx.x;

    if (blockIdx.x < 16) {
        // ================= FPS role =================
        float2* sxy    = (float2*)s_raw;             // 32768 B
        float*  szv    = (float*)(s_raw + 32768);    // 16384 B
        int*    s_cent = (int*)(s_raw + 49152);      //  4096 B
        u64*    s_red  = (u64*)(s_raw + 53248);      //   64 B (2 bufs x 4)

        const int b = blockIdx.x;
        const float* xb = xyz + (size_t)b * NPTS * 3;
        if (tid < 8) s_red[tid] = 0x3FFull;          // tag 1023: no false match at it=0/1
        for (int p = tid; p < NPTS; p += 256) {
            sxy[p] = make_float2(xb[p * 3 + 0], xb[p * 3 + 1]);
            szv[p] = xb[p * 3 + 2];
        }
        __syncthreads();
        float px[16], py[16], pz[16], dist[16];
#pragma unroll
        for (int j = 0; j < 16; ++j) {
            int p = tid + j * 256;
            float2 f = sxy[p];
            px[j] = f.x; py[j] = f.y; pz[j] = szv[p];
            dist[j] = 1e10f;
        }
        const int lane = tid & 63, wid = tid >> 6;
        int far = 0;
        for (int it = 0; it < NPOINT; ++it) {
            if (tid == 0) s_cent[it] = far;
            const float2 cxy = sxy[far];
            const float  cz  = szv[far];
            float bv = -1.0f;
            int   bi = 0;
#pragma unroll
            for (int j = 0; j < 16; ++j) {
                float d  = sqdist(px[j], py[j], pz[j], cxy.x, cxy.y, cz);
                float nd = fminf(dist[j], d);   // jnp.minimum
                dist[j]  = nd;
                if (nd > bv) { bv = nd; bi = tid + j * 256; }  // j asc -> smallest idx on tie
            }
            float red = bv;
            WAVE_RED_F(red);                     // lane63: wave max value
            float gmax = bcast63(red);           // sgpr broadcast to all lanes
            unsigned ienc = (bv == gmax) ? (unsigned)(4095 - bi) : 0u;
            WAVE_RED_U(ienc);                    // lane63: max enc -> smallest idx
            const u64 tag = (u64)(it & 1023);
            if (lane == 63)
                s_red[(it & 1) * 4 + wid] =
                    ((u64)__float_as_uint(red) << 22) | ((u64)ienc << 10) | tag;
            volatile u64* sr = &s_red[(it & 1) * 4];
            u64 k0, k1, k2, k3;
            do {
                k0 = sr[0]; k1 = sr[1]; k2 = sr[2]; k3 = sr[3];
            } while ((((k0 ^ tag) | (k1 ^ tag)) | ((k2 ^ tag) | (k3 ^ tag))) & 0x3FFull);
            u64 w = k0;
            w = (k1 > w) ? k1 : w;
            w = (k2 > w) ? k2 : w;
            w = (k3 > w) ? k3 : w;
            far = 4095 - (int)((w >> 10) & 0xFFFull);
        }
        __syncthreads();
        for (int s = tid; s < NPOINT; s += 256) {
            int c = s_cent[s];
            float2 f = sxy[c];
            new_xyz[((size_t)b * NPOINT + s) * 3 + 0] = f.x;
            new_xyz[((size_t)b * NPOINT + s) * 3 + 1] = f.y;
            new_xyz[((size_t)b * NPOINT + s) * 3 + 2] = szv[c];
        }
    } else {
        // ================= P role: P[n] = W0*[xyz,points]+b0, 64-pt tile =========
        float (*xw)[68] = (float(*)[68])s_raw;             // 17408 B
        float (*wt)[68] = (float(*)[68])(s_raw + 17408);   // 17408 B
        const int blk = blockIdx.x - 16;
        const int pt0 = blk * 64;
        const int ty = tid >> 4, tx = tid & 15;

        for (int idx = tid; idx < 64 * 3; idx += 256) {
            int r = idx / 3, d = idx - r * 3;
            xw[r][d] = xyz[(size_t)(pt0 + r) * 3 + d];
        }
        for (int idx = tid; idx < 64 * 16; idx += 256) {
            int r = idx >> 4, c4 = idx & 15;
            float4 v = *(const float4*)(points + (size_t)(pt0 + r) * CIN + c4 * 4);
            xw[r][3 + c4 * 4 + 0] = v.x;
            xw[r][3 + c4 * 4 + 1] = v.y;
            xw[r][3 + c4 * 4 + 2] = v.z;
            xw[r][3 + c4 * 4 + 3] = v.w;
        }
        for (int idx = tid; idx < 64 * 67; idx += 256) {
            int o = idx / 67, c = idx - o * 67;
            wt[o][c] = w0[idx];
        }
        __syncthreads();

        float acc[4][4];
        {
            float bj[4];
#pragma unroll
            for (int j = 0; j < 4; ++j) bj[j] = b0[tx + 16 * j];
#pragma unroll
            for (int i = 0; i < 4; ++i)
#pragma unroll
                for (int j = 0; j < 4; ++j) acc[i][j] = bj[j];
        }
        for (int c4 = 0; c4 < 64; c4 += 4) {
            float4 xv[4], wv[4];
#pragma unroll
            for (int i = 0; i < 4; ++i) xv[i] = *(const float4*)&xw[ty + 16 * i][c4];
#pragma unroll
            for (int j = 0; j < 4; ++j) wv[j] = *(const float4*)&wt[tx + 16 * j][c4];
#pragma unroll
            for (int i = 0; i < 4; ++i)
#pragma unroll
                for (int j = 0; j < 4; ++j)
                    acc[i][j] += xv[i].x * wv[j].x + xv[i].y * wv[j].y +
                                 xv[i].z * wv[j].z + xv[i].w * wv[j].w;
        }
#pragma unroll
        for (int c = 64; c < 67; ++c) {
            float xv[4], wv[4];
#pragma unroll
            for (int i = 0; i < 4; ++i) xv[i] = xw[ty + 16 * i][c];
#pragma unroll
            for (int j = 0; j < 4; ++j) wv[j] = wt[tx + 16 * j][c];
#pragma unroll
            for (int i = 0; i < 4; ++i)
#pragma unroll
                for (int j = 0; j < 4; ++j) acc[i][j] += xv[i] * wv[j];
        }
#pragma unroll
        for (int i = 0; i < 4; ++i)
#pragma unroll
            for (int j = 0; j < 4; ++j)
                P[(size_t)(pt0 + ty + 16 * i) * 64 + tx + 16 * j] = acc[i][j];
    }
}

// ---------------- ball query (+ fused Q): one wave per (b,s) ----------------
__global__ __launch_bounds__(256) void ballq_kernel(const float* __restrict__ xyz,
                                                    const float* __restrict__ new_xyz,
                                                    const float* __restrict__ w0,
                                                    int* __restrict__ gi,
                                                    float* __restrict__ Q) {
    const int lane = threadIdx.x & 63;
    const int w    = threadIdx.x >> 6;
    const int pair = blockIdx.x * 4 + w;   // b*NPOINT + s
    const int b    = pair >> 10;
    const float R2 = (float)(0.4 * 0.4);
    const float* xb = xyz + (size_t)b * NPTS * 3;
    const float cx = new_xyz[pair * 3 + 0];
    const float cy = new_xyz[pair * 3 + 1];
    const float cz = new_xyz[pair * 3 + 2];
    int* g = gi + (size_t)pair * NSAMP;

    // fused Q[s][lane] = W0xyz row(lane) . centroid
    Q[(size_t)pair * 64 + lane] =
        w0[lane * 67 + 0] * cx + w0[lane * 67 + 1] * cy + w0[lane * 67 + 2] * cz;

    int found = 0, first = 0;
    bool have_first = false;
    for (int c0 = 0; c0 < NPTS; c0 += 64) {
        const int n = c0 + lane;
        float d = sqdist(xb[n * 3 + 0], xb[n * 3 + 1], xb[n * 3 + 2], cx, cy, cz);
        bool in = !(d > R2);
        unsigned long long m = __ballot(in);
        if (m) {
            if (!have_first) { first = c0 + (__ffsll(m) - 1); have_first = true; }
            if (in) {
                int slot = found + (int)__popcll(m & ((1ull << lane) - 1ull));
                if (slot < NSAMP) g[slot] = n;
            }
            found += (int)__popcll(m);
            if (found >= NSAMP) break;
        }
    }
    for (int slot = found + lane; slot < NSAMP; slot += 64) g[slot] = first;
}

// ---------------- stats of raw y0 = P[n] - Q[s] ----------------
__global__ __launch_bounds__(256) void stats0_kernel(
    const float* __restrict__ P, const float* __restrict__ Q,
    const int* __restrict__ gi, float* __restrict__ partial) {
    __shared__ __align__(16) float xw[64][68];
    __shared__ int s_n[64];
    const int tid = threadIdx.x, blk = blockIdx.x;
    const int row0 = blk * 64;
    if (tid < 64) s_n[tid] = ((row0 + tid) >> 15) * NPTS + gi[row0 + tid];
    __syncthreads();
    for (int idx = tid; idx < 64 * 16; idx += 256) {
        int r = idx >> 4, c4 = idx & 15;
        float4 pv = *(const float4*)(P + ((size_t)s_n[r] << 6) + c4 * 4);
        float4 qv = *(const float4*)(Q + ((size_t)(blk * 2 + (r >> 5)) << 6) + c4 * 4);
        float4 y; y.x = pv.x - qv.x; y.y = pv.y - qv.y; y.z = pv.z - qv.z; y.w = pv.w - qv.w;
        *(float4*)&xw[r][c4 * 4] = y;
    }
    __syncthreads();
    if (tid < 64) {
        float s = 0.f, q = 0.f;
        for (int r = 0; r < 64; ++r) { float v = xw[r][tid]; s += v; q += v * v; }
        partial[(size_t)blk * 128 + tid]      = s;
        partial[(size_t)blk * 128 + 64 + tid] = q;
    }
}

// ---------------- chain1: h0 = relu(bn0(P-Q)); y1 = h0*W1+b1; stats ----------------
__global__ __launch_bounds__(256) void chain1_kernel(
    const float* __restrict__ P, const float* __restrict__ Q,
    const int* __restrict__ gi, const float* __restrict__ w1, const float* __restrict__ b1,
    const float* __restrict__ ss, float* __restrict__ partial) {
    __shared__ __align__(16) float xw[64][68];
    __shared__ __align__(16) float wt[64][68];
    __shared__ int s_n[64];
    const int tid = threadIdx.x, blk = blockIdx.x;
    const int row0 = blk * 64;
    const int ty = tid >> 4, tx = tid & 15;

    if (tid < 64) s_n[tid] = ((row0 + tid) >> 15) * NPTS + gi[row0 + tid];
    for (int idx = tid; idx < 64 * 64; idx += 256) {
        int o = idx >> 6, c = idx & 63;
        wt[o][c] = w1[idx];
    }
    __syncthreads();
    for (int idx = tid; idx < 64 * 16; idx += 256) {
        int r = idx >> 4, c4 = idx & 15, c = c4 * 4;
        float4 pv = *(const float4*)(P + ((size_t)s_n[r] << 6) + c);
        float4 qv = *(const float4*)(Q + ((size_t)(blk * 2 + (r >> 5)) << 6) + c);
        float4 y;
        y.x = fmaxf((pv.x - qv.x) * ss[c + 0] + ss[128 + c + 0], 0.f);
        y.y = fmaxf((pv.y - qv.y) * ss[c + 1] + ss[128 + c + 1], 0.f);
        y.z = fmaxf((pv.z - qv.z) * ss[c + 2] + ss[128 + c + 2], 0.f);
        y.w = fmaxf((pv.w - qv.w) * ss[c + 3] + ss[128 + c + 3], 0.f);
        *(float4*)&xw[r][c] = y;
    }
    __syncthreads();

    float acc[4][4];
    {
        float bj[4];
#pragma unroll
        for (int j = 0; j < 4; ++j) bj[j] = b1[tx + 16 * j];
#pragma unroll
        for (int i = 0; i < 4; ++i)
#pragma unroll
            for (int j = 0; j < 4; ++j) acc[i][j] = bj[j];
    }
    for (int c4 = 0; c4 < 64; c4 += 4) {
        float4 xv[4], wv[4];
#pragma unroll
        for (int i = 0; i < 4; ++i) xv[i] = *(const float4*)&xw[ty + 16 * i][c4];
#pragma unroll
        for (int j = 0; j < 4; ++j) wv[j] = *(const float4*)&wt[tx + 16 * j][c4];
#pragma unroll
        for (int i = 0; i < 4; ++i)
#pragma unroll
            for (int j = 0; j < 4; ++j)
                acc[i][j] += xv[i].x * wv[j].x + xv[i].y * wv[j].y +
                             xv[i].z * wv[j].z + xv[i].w * wv[j].w;
    }
    __syncthreads();
#pragma unroll
    for (int i = 0; i < 4; ++i)
#pragma unroll
        for (int j = 0; j < 4; ++j) xw[ty + 16 * i][tx + 16 * j] = acc[i][j];
    __syncthreads();
    if (tid < 64) {
        float s = 0.f, q = 0.f;
        for (int r = 0; r < 64; ++r) { float v = xw[r][tid]; s += v; q += v * v; }
        partial[(size_t)blk * 128 + tid]      = s;
        partial[(size_t)blk * 128 + 64 + tid] = q;
    }
}

// ---------------- chain2: ...bn1+relu; y2 = h1*W2+b2; stats2 + maxpool ----------------
__global__ __launch_bounds__(256) void chain2_kernel(
    const float* __restrict__ P, const float* __restrict__ Q,
    const int* __restrict__ gi,
    const float* __restrict__ w1, const float* __restrict__ b1,
    const float* __restrict__ w2, const float* __restrict__ b2,
    const float* __restrict__ ss, float* __restrict__ partial,
    float* __restrict__ maxy) {
    __shared__ __align__(16) float xw[64][68];
    __shared__ __align__(16) float wt[128][68];
    __shared__ int s_n[64];
    const int tid = threadIdx.x, blk = blockIdx.x;
    const int row0 = blk * 64;
    const int ty = tid >> 4, tx = tid & 15;

    if (tid < 64) s_n[tid] = ((row0 + tid) >> 15) * NPTS + gi[row0 + tid];
    for (int idx = tid; idx < 64 * 64; idx += 256) {
        int o = idx >> 6, c = idx & 63;
        wt[o][c] = w1[idx];
    }
    __syncthreads();
    for (int idx = tid; idx < 64 * 16; idx += 256) {
        int r = idx >> 4, c4 = idx & 15, c = c4 * 4;
        float4 pv = *(const float4*)(P + ((size_t)s_n[r] << 6) + c);
        float4 qv = *(const float4*)(Q + ((size_t)(blk * 2 + (r >> 5)) << 6) + c);
        float4 y;
        y.x = fmaxf((pv.x - qv.x) * ss[c + 0] + ss[128 + c + 0], 0.f);
        y.y = fmaxf((pv.y - qv.y) * ss[c + 1] + ss[128 + c + 1], 0.f);
        y.z = fmaxf((pv.z - qv.z) * ss[c + 2] + ss[128 + c + 2], 0.f);
        y.w = fmaxf((pv.w - qv.w) * ss[c + 3] + ss[128 + c + 3], 0.f);
        *(float4*)&xw[r][c] = y;
    }
    __syncthreads();

    float acc[4][4];
    {
        float bj[4];
#pragma unroll
        for (int j = 0; j < 4; ++j) bj[j] = b1[tx + 16 * j];
#pragma unroll
        for (int i = 0; i < 4; ++i)
#pragma unroll
            for (int j = 0; j < 4; ++j) acc[i][j] = bj[j];
    }
    for (int c4 = 0; c4 < 64; c4 += 4) {
        float4 xv[4], wv[4];
#pragma unroll
        for (int i = 0; i < 4; ++i) xv[i] = *(const float4*)&xw[ty + 16 * i][c4];
#pragma unroll
        for (int j = 0; j < 4; ++j) wv[j] = *(const float4*)&wt[tx + 16 * j][c4];
#pragma unroll
        for (int i = 0; i < 4; ++i)
#pragma unroll
            for (int j = 0; j < 4; ++j)
                acc[i][j] += xv[i].x * wv[j].x + xv[i].y * wv[j].y +
                             xv[i].z * wv[j].z + xv[i].w * wv[j].w;
    }
    __syncthreads();
#pragma unroll
    for (int i = 0; i < 4; ++i)
#pragma unroll
        for (int j = 0; j < 4; ++j) {
            int o = tx + 16 * j;
            xw[ty + 16 * i][o] = fmaxf(acc[i][j] * ss[256 + o] + ss[384 + o], 0.f);
        }
    for (int idx = tid; idx < 128 * 64; idx += 256) {
        int o = idx >> 6, c = idx & 63;
        wt[o][c] = w2[idx];
    }
    __syncthreads();

    float acc2[4][8];
    {
        float bj[8];
#pragma unroll
        for (int j = 0; j < 8; ++j) bj[j] = b2[tx + 16 * j];
#pragma unroll
        for (int i = 0; i < 4; ++i)
#pragma unroll
            for (int j = 0; j < 8; ++j) acc2[i][j] = bj[j];
    }
    for (int c4 = 0; c4 < 64; c4 += 4) {
        float4 xv[4], wv[8];
#pragma unroll
        for (int i = 0; i < 4; ++i) xv[i] = *(const float4*)&xw[ty + 16 * i][c4];
#pragma unroll
        for (int j = 0; j < 8; ++j) wv[j] = *(const float4*)&wt[tx + 16 * j][c4];
#pragma unroll
        for (int i = 0; i < 4; ++i)
#pragma unroll
            for (int j = 0; j < 8; ++j)
                acc2[i][j] += xv[i].x * wv[j].x + xv[i].y * wv[j].y +
                              xv[i].z * wv[j].z + xv[i].w * wv[j].w;
    }

    const int bs0 = blk * 2;
#pragma unroll
    for (int half = 0; half < 2; ++half) {
        __syncthreads();
#pragma unroll
        for (int i = 0; i < 4; ++i)
#pragma unroll
            for (int jj = 0; jj < 4; ++jj)
                xw[ty + 16 * i][tx + 16 * jj] = acc2[i][half * 4 + jj];
        __syncthreads();
        if (tid < 64) {
            float s = 0.f, q = 0.f, m0 = -1e30f, m1 = -1e30f;
            for (int r = 0; r < 32; ++r)  { float v = xw[r][tid]; s += v; q += v * v; m0 = fmaxf(m0, v); }
            for (int r = 32; r < 64; ++r) { float v = xw[r][tid]; s += v; q += v * v; m1 = fmaxf(m1, v); }
            int cg = half * 64 + tid;
            partial[(size_t)blk * 256 + cg]       = s;
            partial[(size_t)blk * 256 + 128 + cg] = q;
            maxy[(size_t)bs0 * 128 + cg]          = m0;
            maxy[(size_t)(bs0 + 1) * 128 + cg]    = m1;
        }
    }
}

// ---------------- reduce stats -> scale/shift ----------------
__global__ __launch_bounds__(256) void reduce_stats_kernel(
    const float* __restrict__ partial, int Cd, float inv_count,
    const float* __restrict__ g, const float* __restrict__ be,
    float* __restrict__ ss_layer) {
    const int c   = blockIdx.x;
    const int tid = threadIdx.x;
    float s = 0.f, q = 0.f;
    for (int blk = tid; blk < NBLK; blk += 256) {
        s += partial[(size_t)blk * 2 * Cd + c];
        q += partial[(size_t)blk * 2 * Cd + Cd + c];
    }
#pragma unroll
    for (int m = 1; m < 64; m <<= 1) { s += __shfl_xor(s, m); q += __shfl_xor(q, m); }
    __shared__ float ls[4], lq[4];
    const int wid = tid >> 6;
    if ((tid & 63) == 0) { ls[wid] = s; lq[wid] = q; }
    __syncthreads();
    if (tid == 0) {
        s = ls[0] + ls[1] + ls[2] + ls[3];
        q = lq[0] + lq[1] + lq[2] + lq[3];
        float mean = s * inv_count;
        float var  = q * inv_count - mean * mean;
        float sc   = g[c] / sqrtf(var + 1e-5f);
        ss_layer[c]       = sc;
        ss_layer[128 + c] = be[c] - mean * sc;
    }
}

// ---------------- final: BN2 + ReLU applied to max-pooled y2 ----------------
__global__ __launch_bounds__(256) void final_kernel(const float* __restrict__ maxy,
                                                    const float* __restrict__ ss2,
                                                    float* __restrict__ outp) {
    int idx = blockIdx.x * 256 + threadIdx.x;
    int c = idx & 127;
    float v = maxy[idx] * ss2[c] + ss2[128 + c];
    outp[idx] = fmaxf(v, 0.f);
}

extern "C" void kernel_launch(void* const* d_in, const int* in_sizes, int n_in,
                              void* d_out, int out_size, void* d_ws, size_t ws_size,
                              hipStream_t stream) {
    const float* xyz    = (const float*)d_in[0];
    const float* points = (const float*)d_in[1];
    const float* w0 = (const float*)d_in[2];  const float* b0  = (const float*)d_in[3];
    const float* g0 = (const float*)d_in[4];  const float* be0 = (const float*)d_in[5];
    const float* w1 = (const float*)d_in[6];  const float* b1  = (const float*)d_in[7];
    const float* g1 = (const float*)d_in[8];  const float* be1 = (const float*)d_in[9];
    const float* w2 = (const float*)d_in[10]; const float* b2  = (const float*)d_in[11];
    const float* g2 = (const float*)d_in[12]; const float* be2 = (const float*)d_in[13];

    float* out      = (float*)d_out;
    float* new_xyz  = out;                                 // [B, S, 3]
    float* out_pts  = out + (size_t)BATCH * NPOINT * 3;    // [B, S, 128]

    char* p = (char*)d_ws;
    int* gi = (int*)p;          p += (((size_t)ROWS * 4) + 255) & ~(size_t)255;
    float* partial = (float*)p; p += (((size_t)NBLK * 256 * 4) + 255) & ~(size_t)255;
    float* ss = (float*)p;      p += ((size_t)(3 * 256 * 4) + 255) & ~(size_t)255;
    float* maxy = (float*)p;    p += (((size_t)BATCH * NPOINT * 128 * 4) + 255) & ~(size_t)255;
    float* P = (float*)p;       p += (((size_t)BATCH * NPTS * 64 * 4) + 255) & ~(size_t)255;
    float* Q = (float*)p;       // [B*NPOINT][64]

    const float inv_count = 1.0f / (float)ROWS;

    pre_kernel<<<16 + 1024, 256, 0, stream>>>(xyz, points, w0, b0, P, new_xyz);
    ballq_kernel<<<(BATCH * NPOINT) / 4, 256, 0, stream>>>(xyz, new_xyz, w0, gi, Q);

    stats0_kernel<<<NBLK, 256, 0, stream>>>(P, Q, gi, partial);
    reduce_stats_kernel<<<64, 256, 0, stream>>>(partial, 64, inv_count, g0, be0, ss + 0);

    chain1_kernel<<<NBLK, 256, 0, stream>>>(P, Q, gi, w1, b1, ss, partial);
    reduce_stats_kernel<<<64, 256, 0, stream>>>(partial, 64, inv_count, g1, be1, ss + 256);

    chain2_kernel<<<NBLK, 256, 0, stream>>>(P, Q, gi, w1, b1, w2, b2, ss, partial, maxy);
    reduce_stats_kernel<<<128, 256, 0, stream>>>(partial, 128, inv_count, g2, be2, ss + 512);

    final_kernel<<<(BATCH * NPOINT * 128) / 256, 256, 0, stream>>>(maxy, ss + 512, out_pts);
}